// Round 15
// baseline (110.606 us; speedup 1.0000x reference)
//
#include <hip/hip_runtime.h>

#define N_ 64
#define C_ 64
#define T_ 256
#define V_ 25
#define R_ 8
#define O_ 64
constexpr int TV = T_ * V_;           // 6400
constexpr float INV_T = 1.0f / (float)T_;
constexpr int TC = 16;                // t's per fused block
constexpr int NPOS = TC * V_;         // 400
constexpr int NT = NPOS / 16;         // 25 MFMA N-tiles
constexpr int DP = 32;                // padded u,v extent of dT
constexpr int UPAD = 40;              // u slots per (o,t) row in x3b
constexpr int X3S = 16 * UPAD + 8;    // 648 halfwords per o_local

typedef __attribute__((ext_vector_type(8))) short s8v;     // 8 bf16
typedef __attribute__((ext_vector_type(4))) float f4v;     // MFMA acc / float4
typedef __attribute__((ext_vector_type(2))) unsigned u2v;  // b64 store

__device__ __forceinline__ unsigned short f2bf(float f) {   // RNE f32->bf16
    union { float f; unsigned u; } v; v.f = f;
    unsigned r = v.u + 0x7FFFu + ((v.u >> 16) & 1u);
    return (unsigned short)(r >> 16);
}
__device__ __forceinline__ unsigned pk2(float a, float b) { // 2 bf16 in a u32
    return (unsigned)f2bf(a) | ((unsigned)f2bf(b) << 16);
}

// -------- k_prep v3: MFMA-identity transpose, ZERO LDS, fused mean.
//   Per (n,tc): for each 32-pos chunk and c-quad cq:
//     A-frag = x[c=cq*16+l16][pos chunk]  (2 coalesced b128 f32 loads -> bf16)
//     c0 = mfma(A, I_lo), c1 = mfma(A, I_hi)   -> xT tiles (lane=pos, regs=4 c)
//     acc += mfma(A, onehot_vclass)            -> temporal-mean partials
//   xT contract identical to r13/r14: byte L = pos*128 + c0*2 ->
//     out[n] + tc*1600 + (L/1600)*TV*4 + L%1600.
__global__ __launch_bounds__(512) void k_prep(const float* __restrict__ x,
                                              float* __restrict__ xm,
                                              float* out) {
    const int n    = blockIdx.y;
    const int tc   = blockIdx.x;
    const int tid  = threadIdx.x;
    const int lane = tid & 63;
    const int wave = tid >> 6;        // 0..7
    const int cq   = wave & 3;        // c-quad (16 c's)
    const int half = wave >> 2;       // chunk half: 0 -> ch 0..6, 1 -> ch 7..12
    const int l16  = lane & 15;
    const int lg   = lane >> 4;       // 0..3

    const float* xr = x + (size_t)(n * C_ + cq * 16 + l16) * TV + tc * NPOS;
    char* xTb = (char*)out + (size_t)n * O_ * TV * 4 + (size_t)tc * 1600;

    // identity B-frags (constant): B[k=lg*8+j][col=l16] = (k == l16 (+16))
    s8v bi_lo, bi_hi;
    #pragma unroll
    for (int j = 0; j < 8; ++j) {
        const int k = lg * 8 + j;
        bi_lo[j] = (short)((k == l16)      ? 0x3F80 : 0);
        bi_hi[j] = (short)((k == l16 + 16) ? 0x3F80 : 0);
    }

    f4v acc0 = (f4v)0.f, acc1 = (f4v)0.f;   // mean partials: v=l16 / v=16+l16

    const int ch0 = half * 7, ch1 = half ? 13 : 7;
    #pragma unroll 1
    for (int ch = ch0; ch < ch1; ++ch) {
        const int posbase = ch * 32;
        int off = posbase + lg * 8;
        if (off >= NPOS) off = NPOS - 16;     // tail clamp (ch12,lg>=2): values
                                              // never selected by bi_lo/bm
        const f4v xa = *(const f4v*)(xr + off);
        const f4v xb = *(const f4v*)(xr + off + 4);
        s8v afr;
        {
            unsigned* ap = (unsigned*)&afr;
            ap[0] = pk2(xa[0], xa[1]); ap[1] = pk2(xa[2], xa[3]);
            ap[2] = pk2(xb[0], xb[1]); ap[3] = pk2(xb[2], xb[3]);
        }

        // transpose: C[row=c(lg*4+r)][col=pos'] ; c0: pos'=posbase+l16, c1: +16
        f4v c0 = (f4v)0.f, c1 = (f4v)0.f;
        c0 = __builtin_amdgcn_mfma_f32_16x16x32_bf16(afr, bi_lo, c0, 0, 0, 0);
        c1 = __builtin_amdgcn_mfma_f32_16x16x32_bf16(afr, bi_hi, c1, 0, 0, 0);

        // mean one-hot B: B[k][v] = 1 iff (posbase+k) % 25 == v  (and pos < 400)
        s8v bm_lo, bm_hi;
        {
            const int kb = posbase + lg * 8;
            int m = kb % 25;
            #pragma unroll
            for (int j = 0; j < 8; ++j) {
                const bool valid = (kb + j) < NPOS;
                bm_lo[j] = (short)((valid && m == l16)      ? 0x3F80 : 0);
                bm_hi[j] = (short)((valid && m == l16 + 16) ? 0x3F80 : 0);
                if (++m == 25) m = 0;
            }
        }
        acc0 = __builtin_amdgcn_mfma_f32_16x16x32_bf16(afr, bm_lo, acc0, 0, 0, 0);
        acc1 = __builtin_amdgcn_mfma_f32_16x16x32_bf16(afr, bm_hi, acc1, 0, 0, 0);

        // write c0 (always in range): b64 = 4 bf16 (c..c+3) at pos'=posbase+l16
        {
            const int pos = posbase + l16;
            const int L = pos * 128 + (cq * 16 + lg * 4) * 2;
            const int row = L / 1600, o = L - row * 1600;
            *(u2v*)(xTb + (size_t)row * (TV * 4) + o) =
                u2v{pk2(c0[0], c0[1]), pk2(c0[2], c0[3])};
        }
        // write c1 (pos'=posbase+16+l16; skipped entirely for ch==12)
        if (posbase + 16 + l16 < NPOS) {
            const int pos = posbase + 16 + l16;
            const int L = pos * 128 + (cq * 16 + lg * 4) * 2;
            const int row = L / 1600, o = L - row * 1600;
            *(u2v*)(xTb + (size_t)row * (TV * 4) + o) =
                u2v{pk2(c1[0], c1[1]), pk2(c1[2], c1[3])};
        }
    }

    // mean partials -> global (bins get 2 halves x 16 tc adds each)
    const int cb = cq * 16 + lg * 4;
    float* xb0 = xm + (size_t)n * C_ * V_;
    #pragma unroll
    for (int r = 0; r < 4; ++r)
        atomicAdd(&xb0[(cb + r) * V_ + l16], acc0[r] * INV_T);
    if (l16 < 9) {
        #pragma unroll
        for (int r = 0; r < 4; ++r)
            atomicAdd(&xb0[(cb + r) * V_ + 16 + l16], acc1[r] * INV_T);
    }
}

// -------- k_dmat: dT[n][o][v][u] = d(u,v) bf16, zero-padded to 32x32. (r13)
__global__ __launch_bounds__(256) void k_dmat(const float* __restrict__ xm,
                                              const float* __restrict__ A,
                                              const float* __restrict__ w1,
                                              const float* __restrict__ b1,
                                              const float* __restrict__ w2,
                                              const float* __restrict__ b2,
                                              const float* __restrict__ w4,
                                              const float* __restrict__ b4,
                                              unsigned short* __restrict__ dT) {
    __shared__ float xms[C_][V_];
    __shared__ float x1s[R_][V_];
    __shared__ float x2s[R_][V_];
    const int n  = blockIdx.x;
    const int og = blockIdx.y * 8;
    const int tid = threadIdx.x;

    for (int i = tid; i < C_ * V_; i += 256)
        xms[i / V_][i % V_] = xm[(size_t)n * C_ * V_ + i];
    __syncthreads();

    for (int i = tid; i < 2 * R_ * V_; i += 256) {
        const int j = i % (R_ * V_);
        const int r = j / V_, v = j % V_;
        const bool first = (i < R_ * V_);
        const float* w = first ? w1 : w2;
        float acc = first ? b1[r] : b2[r];
        #pragma unroll
        for (int c = 0; c < C_; ++c) acc += w[r * C_ + c] * xms[c][v];
        if (first) x1s[r][v] = acc;
        else       x2s[r][v] = acc;
    }
    __syncthreads();

    unsigned short* dn = dT + (size_t)n * O_ * DP * DP;
    for (int p = tid; p < DP * DP; p += 256) {       // p = v*32+u
        const int v = p >> 5, u = p & 31;
        if (u < V_ && v < V_) {
            float adjr[R_];
            #pragma unroll
            for (int r = 0; r < R_; ++r) adjr[r] = tanhf(x1s[r][u] - x2s[r][v]);
            const float a = A[u * V_ + v];
            #pragma unroll
            for (int oo = 0; oo < 8; ++oo) {
                const int o = og + oo;
                float acc = b4[o];
                #pragma unroll
                for (int r = 0; r < R_; ++r) acc = fmaf(w4[o * R_ + r], adjr[r], acc);
                dn[(size_t)o * DP * DP + p] = f2bf(acc + a);   // ALPHA == 1
            }
        } else {
            #pragma unroll
            for (int oo = 0; oo < 8; ++oo)
                dn[(size_t)(og + oo) * DP * DP + p] = 0;
        }
    }
}

// -------- k_F v6 (r13/r14, validated ~23us): B-frags = single b128 loads from
//          pre-transposed xT (in this block's own d_out region); x3b-only LDS.
__global__ __launch_bounds__(512) void k_F(const float* __restrict__ w3,
                                           const float* __restrict__ b3,
                                           const unsigned short* __restrict__ dT,
                                           float* io) {
    __shared__ __align__(16) unsigned short x3b[16 * X3S];        // 20736 B

    const int n    = blockIdx.y;
    const int tc   = blockIdx.x;
    const int tid  = threadIdx.x;
    const int lane = tid & 63;
    const int wave = tid >> 6;      // 0..7
    const int l16  = lane & 15;
    const int lg   = lane >> 4;     // 0..3

    // zero x3b u-pad [24,32): [25,32) must be 0 for GEMM2's K=32
    if (tid < 256) {
        const int o_l = tid >> 4, t = tid & 15;
        *(s8v*)&x3b[o_l * X3S + t * UPAD + 24] = (s8v)0;
    }
    __syncthreads();

    // ---- hoist B-frags: 8 independent b128 loads from xT
    const char* xTb = (const char*)io + (size_t)n * O_ * TV * 4 + (size_t)tc * 1600;
    s8v bfr[4][2];
    #pragma unroll
    for (int i = 0; i < 4; ++i) {
        const int nt = wave + 8 * i;
        if (nt < NT) {
            const int pos = nt * 16 + l16;
            #pragma unroll
            for (int kh = 0; kh < 2; ++kh) {
                const int L = pos * 128 + kh * 64 + lg * 16;
                const int row = L / 1600, off = L - row * 1600;
                bfr[i][kh] = *(const s8v*)(xTb + (size_t)row * (TV * 4) + off);
            }
        }
    }

    const unsigned short* dn = dT + (size_t)n * O_ * DP * DP;
    float* on = io + (size_t)n * O_ * TV + tc * NPOS;

    #pragma unroll 1
    for (int h = 0; h < 4; ++h) {               // o-quarter: o = h*16 .. h*16+15
        // A-frags (w3 L1/L2-resident)
        s8v afr[2];
        #pragma unroll
        for (int kh = 0; kh < 2; ++kh) {
            const float* wp = w3 + (h * 16 + l16) * C_ + kh * 32 + lg * 8;
            s8v f;
            #pragma unroll
            for (int j = 0; j < 8; ++j) f[j] = (short)f2bf(wp[j]);
            afr[kh] = f;
        }
        const f4v b3h = *(const f4v*)(b3 + h * 16 + lg * 4);

        // GEMM1 quarter
        #pragma unroll
        for (int i = 0; i < 4; ++i) {
            const int nt = wave + 8 * i;
            if (nt < NT) {
                const int pos = nt * 16 + l16;
                const int t = pos / 25, u = pos - 25 * t;
                f4v acc = (f4v)0.f;
                acc = __builtin_amdgcn_mfma_f32_16x16x32_bf16(afr[0], bfr[i][0], acc, 0, 0, 0);
                acc = __builtin_amdgcn_mfma_f32_16x16x32_bf16(afr[1], bfr[i][1], acc, 0, 0, 0);
                #pragma unroll
                for (int r = 0; r < 4; ++r)
                    x3b[(lg * 4 + r) * X3S + t * UPAD + u] = f2bf(acc[r] + b3h[r]);
            }
        }
        __syncthreads();   // B1: x3b ready (h=0: also fences xT reads vs stores)

        // GEMM2 quarter: wave owns o_l = wave*2 + {0,1}
        #pragma unroll
        for (int oo = 0; oo < 2; ++oo) {
            const int o_l = wave * 2 + oo;
            const int o_g = h * 16 + o_l;
            const unsigned short* dp = dn + (size_t)o_g * DP * DP;
            const s8v bv0 = *(const s8v*)(dp + l16 * DP + lg * 8);
            const s8v bv1 = *(const s8v*)(dp + (16 + l16) * DP + lg * 8);
            const s8v av  = *(const s8v*)&x3b[o_l * X3S + l16 * UPAD + lg * 8];
            f4v c0 = (f4v)0.f, c1 = (f4v)0.f;
            c0 = __builtin_amdgcn_mfma_f32_16x16x32_bf16(av, bv0, c0, 0, 0, 0);
            c1 = __builtin_amdgcn_mfma_f32_16x16x32_bf16(av, bv1, c1, 0, 0, 0);
            float* ob = on + (size_t)o_g * TV;
            #pragma unroll
            for (int r = 0; r < 4; ++r) {
                const int t = lg * 4 + r;                       // C: row=t, col=v
                ob[t * 25 + l16] = c0[r];
                if (l16 < 9) ob[t * 25 + 16 + l16] = c1[r];
            }
        }
        __syncthreads();   // B2: protect x3b before next quarter's GEMM1
    }
}

extern "C" void kernel_launch(void* const* d_in, const int* in_sizes, int n_in,
                              void* d_out, int out_size, void* d_ws, size_t ws_size,
                              hipStream_t stream) {
    const float* x  = (const float*)d_in[0];
    const float* A  = (const float*)d_in[1];
    const float* w1 = (const float*)d_in[2];
    const float* b1 = (const float*)d_in[3];
    const float* w2 = (const float*)d_in[4];
    const float* b2 = (const float*)d_in[5];
    const float* w3 = (const float*)d_in[6];
    const float* b3 = (const float*)d_in[7];
    const float* w4 = (const float*)d_in[8];
    const float* b4 = (const float*)d_in[9];

    float* out = (float*)d_out;
    float* xm  = (float*)d_ws;                                          // 0.41 MB f32
    unsigned short* dTm = (unsigned short*)(xm + (size_t)N_ * C_ * V_); // 8.4 MB bf16

    hipMemsetAsync(xm, 0, (size_t)N_ * C_ * V_ * sizeof(float), stream);
    k_prep<<<dim3(T_ / TC, N_), 512, 0, stream>>>(x, xm, out);
    k_dmat<<<dim3(N_, 8), 256, 0, stream>>>(xm, A, w1, b1, w2, b2, w4, b4, dTm);
    k_F<<<dim3(T_ / TC, N_), 512, 0, stream>>>(w3, b3, dTm, out);
}

// Round 16
// 102.865 us; speedup vs baseline: 1.0753x; 1.0753x over previous
//
#include <hip/hip_runtime.h>

#define N_ 64
#define C_ 64
#define T_ 256
#define V_ 25
#define R_ 8
#define O_ 64
constexpr int TV = T_ * V_;           // 6400
constexpr float INV_T = 1.0f / (float)T_;
constexpr int TC = 16;                // t's per fused block
constexpr int NPOS = TC * V_;         // 400
constexpr int NT = NPOS / 16;         // 25 MFMA N-tiles
constexpr int DP = 32;                // padded u,v extent of dT
constexpr int UPAD = 40;              // u slots per (o,t) row in x3b
constexpr int X3S = 16 * UPAD + 8;    // 648 halfwords per o_local
constexpr int CV = C_ * V_;           // 1600

typedef __attribute__((ext_vector_type(8))) short s8v;     // 8 bf16
typedef __attribute__((ext_vector_type(4))) float f4v;     // MFMA acc / float4
typedef __attribute__((ext_vector_type(2))) unsigned u2v;  // b64 store

__device__ __forceinline__ unsigned short f2bf(float f) {   // RNE f32->bf16
    union { float f; unsigned u; } v; v.f = f;
    unsigned r = v.u + 0x7FFFu + ((v.u >> 16) & 1u);
    return (unsigned short)(r >> 16);
}
__device__ __forceinline__ unsigned pk2(float a, float b) { // 2 bf16 in a u32
    return (unsigned)f2bf(a) | ((unsigned)f2bf(b) << 16);
}

// -------- k_prep v4: MFMA-identity transpose (r15, verified) with the global
//   atomics replaced by LDS half-reduce + per-block partial row (NO atomics).
//   xT contract identical to r13..r15.
__global__ __launch_bounds__(512) void k_prep(const float* __restrict__ x,
                                              float* __restrict__ xmp,   // [N*16][1600]
                                              float* out) {
    __shared__ float msum[2 * CV];        // 12.8 KB: [half][c*25+v]
    const int n    = blockIdx.y;
    const int tc   = blockIdx.x;
    const int tid  = threadIdx.x;
    const int lane = tid & 63;
    const int wave = tid >> 6;        // 0..7
    const int cq   = wave & 3;        // c-quad (16 c's)
    const int half = wave >> 2;       // chunk half: 0 -> ch 0..6, 1 -> ch 7..12
    const int l16  = lane & 15;
    const int lg   = lane >> 4;       // 0..3

    const float* xr = x + (size_t)(n * C_ + cq * 16 + l16) * TV + tc * NPOS;
    char* xTb = (char*)out + (size_t)n * O_ * TV * 4 + (size_t)tc * 1600;

    // identity B-frags: B[k=lg*8+j][col=l16] = (k == l16 (+16))
    s8v bi_lo, bi_hi;
    #pragma unroll
    for (int j = 0; j < 8; ++j) {
        const int k = lg * 8 + j;
        bi_lo[j] = (short)((k == l16)      ? 0x3F80 : 0);
        bi_hi[j] = (short)((k == l16 + 16) ? 0x3F80 : 0);
    }

    f4v acc0 = (f4v)0.f, acc1 = (f4v)0.f;   // mean partials: v=l16 / v=16+l16

    const int ch0 = half * 7, ch1 = half ? 13 : 7;
    #pragma unroll 2
    for (int ch = ch0; ch < ch1; ++ch) {
        const int posbase = ch * 32;
        int off = posbase + lg * 8;
        if (off >= NPOS) off = NPOS - 16;     // tail clamp (ch12,lg>=2): values
                                              // never selected by bi/bm
        const f4v xa = *(const f4v*)(xr + off);
        const f4v xb = *(const f4v*)(xr + off + 4);
        s8v afr;
        {
            unsigned* ap = (unsigned*)&afr;
            ap[0] = pk2(xa[0], xa[1]); ap[1] = pk2(xa[2], xa[3]);
            ap[2] = pk2(xb[0], xb[1]); ap[3] = pk2(xb[2], xb[3]);
        }

        // transpose: C[row=c(lg*4+r)][col=pos'] ; c0: pos'=posbase+l16, c1: +16
        f4v c0 = (f4v)0.f, c1 = (f4v)0.f;
        c0 = __builtin_amdgcn_mfma_f32_16x16x32_bf16(afr, bi_lo, c0, 0, 0, 0);
        c1 = __builtin_amdgcn_mfma_f32_16x16x32_bf16(afr, bi_hi, c1, 0, 0, 0);

        // mean one-hot B: B[k][v] = 1 iff (posbase+k) % 25 == v  (and pos < 400)
        s8v bm_lo, bm_hi;
        {
            const int kb = posbase + lg * 8;
            int m = kb % 25;
            #pragma unroll
            for (int j = 0; j < 8; ++j) {
                const bool valid = (kb + j) < NPOS;
                bm_lo[j] = (short)((valid && m == l16)      ? 0x3F80 : 0);
                bm_hi[j] = (short)((valid && m == l16 + 16) ? 0x3F80 : 0);
                if (++m == 25) m = 0;
            }
        }
        acc0 = __builtin_amdgcn_mfma_f32_16x16x32_bf16(afr, bm_lo, acc0, 0, 0, 0);
        acc1 = __builtin_amdgcn_mfma_f32_16x16x32_bf16(afr, bm_hi, acc1, 0, 0, 0);

        // write c0: b64 = 4 bf16 (c..c+3) at pos'=posbase+l16
        {
            const int pos = posbase + l16;
            const int L = pos * 128 + (cq * 16 + lg * 4) * 2;
            const int row = L / 1600, o = L - row * 1600;
            *(u2v*)(xTb + (size_t)row * (TV * 4) + o) =
                u2v{pk2(c0[0], c0[1]), pk2(c0[2], c0[3])};
        }
        // write c1 (pos'=posbase+16+l16; skipped entirely for ch==12)
        if (posbase + 16 + l16 < NPOS) {
            const int pos = posbase + 16 + l16;
            const int L = pos * 128 + (cq * 16 + lg * 4) * 2;
            const int row = L / 1600, o = L - row * 1600;
            *(u2v*)(xTb + (size_t)row * (TV * 4) + o) =
                u2v{pk2(c1[0], c1[1]), pk2(c1[2], c1[3])};
        }
    }

    // mean partials -> LDS (each bin written exactly once per half; no atomics)
    {
        float* ms = msum + half * CV;
        const int cb = cq * 16 + lg * 4;
        #pragma unroll
        for (int r = 0; r < 4; ++r)
            ms[(cb + r) * V_ + l16] = acc0[r];
        if (l16 < 9) {
            #pragma unroll
            for (int r = 0; r < 4; ++r)
                ms[(cb + r) * V_ + 16 + l16] = acc1[r];
        }
    }
    __syncthreads();

    // reduce the two halves -> this block's private partial row (coalesced)
    float* xp = xmp + (size_t)(n * 16 + tc) * CV;
    #pragma unroll
    for (int i = tid; i < CV; i += 512)
        xp[i] = msum[i] + msum[CV + i];
}

// -------- k_red: xm[n][cv] = INV_T * sum_tc xmp[n*16+tc][cv]   (~3us)
__global__ __launch_bounds__(256) void k_red(const float* __restrict__ xmp,
                                             float* __restrict__ xm) {
    const int n   = blockIdx.x;
    const int tid = threadIdx.x;
    const float* base = xmp + (size_t)n * 16 * CV;
    for (int i = tid; i < CV; i += 256) {
        float s = 0.f;
        #pragma unroll
        for (int t = 0; t < 16; ++t) s += base[t * CV + i];
        xm[(size_t)n * CV + i] = s * INV_T;
    }
}

// -------- k_dmat: dT[n][o][v][u] = d(u,v) bf16, zero-padded to 32x32. (r13)
__global__ __launch_bounds__(256) void k_dmat(const float* __restrict__ xm,
                                              const float* __restrict__ A,
                                              const float* __restrict__ w1,
                                              const float* __restrict__ b1,
                                              const float* __restrict__ w2,
                                              const float* __restrict__ b2,
                                              const float* __restrict__ w4,
                                              const float* __restrict__ b4,
                                              unsigned short* __restrict__ dT) {
    __shared__ float xms[C_][V_];
    __shared__ float x1s[R_][V_];
    __shared__ float x2s[R_][V_];
    const int n  = blockIdx.x;
    const int og = blockIdx.y * 8;
    const int tid = threadIdx.x;

    for (int i = tid; i < C_ * V_; i += 256)
        xms[i / V_][i % V_] = xm[(size_t)n * C_ * V_ + i];
    __syncthreads();

    for (int i = tid; i < 2 * R_ * V_; i += 256) {
        const int j = i % (R_ * V_);
        const int r = j / V_, v = j % V_;
        const bool first = (i < R_ * V_);
        const float* w = first ? w1 : w2;
        float acc = first ? b1[r] : b2[r];
        #pragma unroll
        for (int c = 0; c < C_; ++c) acc += w[r * C_ + c] * xms[c][v];
        if (first) x1s[r][v] = acc;
        else       x2s[r][v] = acc;
    }
    __syncthreads();

    unsigned short* dn = dT + (size_t)n * O_ * DP * DP;
    for (int p = tid; p < DP * DP; p += 256) {       // p = v*32+u
        const int v = p >> 5, u = p & 31;
        if (u < V_ && v < V_) {
            float adjr[R_];
            #pragma unroll
            for (int r = 0; r < R_; ++r) adjr[r] = tanhf(x1s[r][u] - x2s[r][v]);
            const float a = A[u * V_ + v];
            #pragma unroll
            for (int oo = 0; oo < 8; ++oo) {
                const int o = og + oo;
                float acc = b4[o];
                #pragma unroll
                for (int r = 0; r < R_; ++r) acc = fmaf(w4[o * R_ + r], adjr[r], acc);
                dn[(size_t)o * DP * DP + p] = f2bf(acc + a);   // ALPHA == 1
            }
        } else {
            #pragma unroll
            for (int oo = 0; oo < 8; ++oo)
                dn[(size_t)(og + oo) * DP * DP + p] = 0;
        }
    }
}

// -------- k_F v6 (r13..r15, validated ~23us): B-frags = single b128 loads from
//          pre-transposed xT (in this block's own d_out region); x3b-only LDS.
__global__ __launch_bounds__(512) void k_F(const float* __restrict__ w3,
                                           const float* __restrict__ b3,
                                           const unsigned short* __restrict__ dT,
                                           float* io) {
    __shared__ __align__(16) unsigned short x3b[16 * X3S];        // 20736 B

    const int n    = blockIdx.y;
    const int tc   = blockIdx.x;
    const int tid  = threadIdx.x;
    const int lane = tid & 63;
    const int wave = tid >> 6;      // 0..7
    const int l16  = lane & 15;
    const int lg   = lane >> 4;     // 0..3

    // zero x3b u-pad [24,32): [25,32) must be 0 for GEMM2's K=32
    if (tid < 256) {
        const int o_l = tid >> 4, t = tid & 15;
        *(s8v*)&x3b[o_l * X3S + t * UPAD + 24] = (s8v)0;
    }
    __syncthreads();

    // ---- hoist B-frags: 8 independent b128 loads from xT
    const char* xTb = (const char*)io + (size_t)n * O_ * TV * 4 + (size_t)tc * 1600;
    s8v bfr[4][2];
    #pragma unroll
    for (int i = 0; i < 4; ++i) {
        const int nt = wave + 8 * i;
        if (nt < NT) {
            const int pos = nt * 16 + l16;
            #pragma unroll
            for (int kh = 0; kh < 2; ++kh) {
                const int L = pos * 128 + kh * 64 + lg * 16;
                const int row = L / 1600, off = L - row * 1600;
                bfr[i][kh] = *(const s8v*)(xTb + (size_t)row * (TV * 4) + off);
            }
        }
    }

    const unsigned short* dn = dT + (size_t)n * O_ * DP * DP;
    float* on = io + (size_t)n * O_ * TV + tc * NPOS;

    #pragma unroll 1
    for (int h = 0; h < 4; ++h) {               // o-quarter: o = h*16 .. h*16+15
        // A-frags (w3 L1/L2-resident)
        s8v afr[2];
        #pragma unroll
        for (int kh = 0; kh < 2; ++kh) {
            const float* wp = w3 + (h * 16 + l16) * C_ + kh * 32 + lg * 8;
            s8v f;
            #pragma unroll
            for (int j = 0; j < 8; ++j) f[j] = (short)f2bf(wp[j]);
            afr[kh] = f;
        }
        const f4v b3h = *(const f4v*)(b3 + h * 16 + lg * 4);

        // GEMM1 quarter
        #pragma unroll
        for (int i = 0; i < 4; ++i) {
            const int nt = wave + 8 * i;
            if (nt < NT) {
                const int pos = nt * 16 + l16;
                const int t = pos / 25, u = pos - 25 * t;
                f4v acc = (f4v)0.f;
                acc = __builtin_amdgcn_mfma_f32_16x16x32_bf16(afr[0], bfr[i][0], acc, 0, 0, 0);
                acc = __builtin_amdgcn_mfma_f32_16x16x32_bf16(afr[1], bfr[i][1], acc, 0, 0, 0);
                #pragma unroll
                for (int r = 0; r < 4; ++r)
                    x3b[(lg * 4 + r) * X3S + t * UPAD + u] = f2bf(acc[r] + b3h[r]);
            }
        }
        __syncthreads();   // B1: x3b ready (h=0: also fences xT reads vs stores)

        // GEMM2 quarter: wave owns o_l = wave*2 + {0,1}
        #pragma unroll
        for (int oo = 0; oo < 2; ++oo) {
            const int o_l = wave * 2 + oo;
            const int o_g = h * 16 + o_l;
            const unsigned short* dp = dn + (size_t)o_g * DP * DP;
            const s8v bv0 = *(const s8v*)(dp + l16 * DP + lg * 8);
            const s8v bv1 = *(const s8v*)(dp + (16 + l16) * DP + lg * 8);
            const s8v av  = *(const s8v*)&x3b[o_l * X3S + l16 * UPAD + lg * 8];
            f4v c0 = (f4v)0.f, c1 = (f4v)0.f;
            c0 = __builtin_amdgcn_mfma_f32_16x16x32_bf16(av, bv0, c0, 0, 0, 0);
            c1 = __builtin_amdgcn_mfma_f32_16x16x32_bf16(av, bv1, c1, 0, 0, 0);
            float* ob = on + (size_t)o_g * TV;
            #pragma unroll
            for (int r = 0; r < 4; ++r) {
                const int t = lg * 4 + r;                       // C: row=t, col=v
                ob[t * 25 + l16] = c0[r];
                if (l16 < 9) ob[t * 25 + 16 + l16] = c1[r];
            }
        }
        __syncthreads();   // B2: protect x3b before next quarter's GEMM1
    }
}

extern "C" void kernel_launch(void* const* d_in, const int* in_sizes, int n_in,
                              void* d_out, int out_size, void* d_ws, size_t ws_size,
                              hipStream_t stream) {
    const float* x  = (const float*)d_in[0];
    const float* A  = (const float*)d_in[1];
    const float* w1 = (const float*)d_in[2];
    const float* b1 = (const float*)d_in[3];
    const float* w2 = (const float*)d_in[4];
    const float* b2 = (const float*)d_in[5];
    const float* w3 = (const float*)d_in[6];
    const float* b3 = (const float*)d_in[7];
    const float* w4 = (const float*)d_in[8];
    const float* b4 = (const float*)d_in[9];

    float* out = (float*)d_out;
    float* xm  = (float*)d_ws;                                          // 0.41 MB f32
    unsigned short* dTm = (unsigned short*)(xm + (size_t)N_ * CV);      // 8.4 MB bf16
    float* xmp = (float*)(dTm + (size_t)N_ * O_ * DP * DP);             // 6.6 MB f32

    k_prep<<<dim3(T_ / TC, N_), 512, 0, stream>>>(x, xmp, out);
    k_red<<<N_, 256, 0, stream>>>(xmp, xm);
    k_dmat<<<dim3(N_, 8), 256, 0, stream>>>(xm, A, w1, b1, w2, b2, w4, b4, dTm);
    k_F<<<dim3(T_ / TC, N_), 512, 0, stream>>>(w3, b3, dTm, out);
}

// Round 17
// 97.426 us; speedup vs baseline: 1.1353x; 1.0558x over previous
//
#include <hip/hip_runtime.h>

#define N_ 64
#define C_ 64
#define T_ 256
#define V_ 25
#define R_ 8
#define O_ 64
constexpr int TV = T_ * V_;           // 6400
constexpr float INV_T = 1.0f / (float)T_;
constexpr int TC = 16;                // t's per k_F block
constexpr int NPOS = TC * V_;         // 400
constexpr int NT = NPOS / 16;         // 25 MFMA N-tiles
constexpr int DP = 32;                // padded u,v extent of dT
constexpr int UPAD = 40;              // u slots per (o,t) row in x3b
constexpr int X3S = 16 * UPAD + 8;    // 648 halfwords per o_local
constexpr int CV = C_ * V_;           // 1600
constexpr int LSTR = 210;             // LDS c-row stride (halfwords): even (4B-
                                      // aligned b32 writes), banks spread on
                                      // 8-row gather (4-way max)

typedef __attribute__((ext_vector_type(8))) short s8v;     // 8 bf16
typedef __attribute__((ext_vector_type(4))) float f4v;     // MFMA acc / float4

__device__ __forceinline__ unsigned short f2bf(float f) {   // RNE f32->bf16
    union { float f; unsigned u; } v; v.f = f;
    unsigned r = v.u + 0x7FFFu + ((v.u >> 16) & 1u);
    return (unsigned short)(r >> 16);
}
__device__ __forceinline__ unsigned pk2(float a, float b) { // 2 bf16 in a u32
    return (unsigned)f2bf(a) | ((unsigned)f2bf(b) << 16);
}
__device__ __forceinline__ float bf2f(unsigned short h) {
    union { unsigned u; float f; } v; v.u = (unsigned)h << 16; return v.f;
}

// -------- k_prep v5: tight-VMEM transpose. Per (n, ph): 200-pos chunk,
//   all 64 c. Stage coalesced b128 -> LDS [c][pos] bf16 -> (a) emit xT rows
//   via fully-coalesced b128 stores, (b) mean partials (8 t's) -> xmp, no
//   atomics. xT contract unchanged from r13..r16.
__global__ __launch_bounds__(256) void k_prep(const float* __restrict__ x,
                                              float* __restrict__ xmp,  // [N*32][CV]
                                              float* out) {
    __shared__ unsigned short lx[C_ * LSTR];    // 26880 B -> 6 blocks/CU
    const int n    = blockIdx.y;
    const int ph   = blockIdx.x;       // 0..31
    const int tid  = threadIdx.x;
    const int tc   = ph >> 1;
    const int poff = (ph & 1) * 200;   // pos offset inside tc chunk

    const float* xb = x + (size_t)n * C_ * TV + tc * NPOS + poff;
    char* xTb = (char*)out + (size_t)n * O_ * TV * 4 + (size_t)tc * 1600;

    // stage: 3200 items (c, p4): coalesced b128 loads (800-B runs per c row),
    // two 4B-aligned packed LDS writes each (stride-8B lanes -> <=4-way banks)
    #pragma unroll
    for (int i = 0; i < 13; ++i) {
        const int s = i * 256 + tid;
        if (s < 3200) {
            const int c = s / 50, p4 = s - c * 50;
            const f4v v = *(const f4v*)(xb + (size_t)c * TV + p4 * 4);
            unsigned* p = (unsigned*)&lx[c * LSTR + p4 * 4];
            p[0] = pk2(v[0], v[1]);
            p[1] = pk2(v[2], v[3]);
        }
    }
    __syncthreads();

    // transpose-emit: 1600 items (pos, cg): 8 scalar LDS reads (banks spread
    // by stride-210: cg -> 4 groups, pos pairs -> 4; ~4-way worst) ->
    // ONE b128 store; lanes cg0..7 then pos -> contiguous 1-KB runs.
    #pragma unroll 2
    for (int i = 0; i < 7; ++i) {
        const int it = i * 256 + tid;
        if (it < 1600) {
            const int pos = it >> 3, cg = it & 7;
            s8v pk;
            #pragma unroll
            for (int j = 0; j < 8; ++j)
                pk[j] = (short)lx[(cg * 8 + j) * LSTR + pos];
            const int L = (poff + pos) * 128 + cg * 16;
            const int row = L / 1600, off = L - row * 1600;
            *(s8v*)(xTb + (size_t)row * (TV * 4) + off) = pk;
        }
    }

    // mean partials over this chunk's 8 t's (read-only on lx; no 2nd barrier)
    float* xp = xmp + (size_t)(n * 32 + ph) * CV;
    #pragma unroll 2
    for (int i = 0; i < 7; ++i) {
        const int p = i * 256 + tid;
        if (p < CV) {
            const int c = p / V_, v = p - c * V_;
            float s = 0.f;
            #pragma unroll
            for (int t = 0; t < 8; ++t) s += bf2f(lx[c * LSTR + t * V_ + v]);
            xp[p] = s;   // coalesced
        }
    }
}

// -------- k_red: xm[n][i] = INV_T * sum_ph xmp[n*32+ph][i]
__global__ __launch_bounds__(256) void k_red(const float* __restrict__ xmp,
                                             float* __restrict__ xm) {
    const int n   = blockIdx.x >> 2;
    const int sg  = blockIdx.x & 3;       // 400-elem segment
    const int i0  = sg * 400;
    const int tid = threadIdx.x;
    const float* base = xmp + (size_t)n * 32 * CV;
    for (int i = i0 + tid; i < i0 + 400; i += 256) {
        float s = 0.f;
        #pragma unroll
        for (int t = 0; t < 32; ++t) s += base[t * CV + i];
        xm[(size_t)n * CV + i] = s * INV_T;
    }
}

// -------- k_dmat: dT[n][o][v][u] = d(u,v) bf16, zero-padded to 32x32. (r13)
__global__ __launch_bounds__(256) void k_dmat(const float* __restrict__ xm,
                                              const float* __restrict__ A,
                                              const float* __restrict__ w1,
                                              const float* __restrict__ b1,
                                              const float* __restrict__ w2,
                                              const float* __restrict__ b2,
                                              const float* __restrict__ w4,
                                              const float* __restrict__ b4,
                                              unsigned short* __restrict__ dT) {
    __shared__ float xms[C_][V_];
    __shared__ float x1s[R_][V_];
    __shared__ float x2s[R_][V_];
    const int n  = blockIdx.x;
    const int og = blockIdx.y * 8;
    const int tid = threadIdx.x;

    for (int i = tid; i < C_ * V_; i += 256)
        xms[i / V_][i % V_] = xm[(size_t)n * C_ * V_ + i];
    __syncthreads();

    for (int i = tid; i < 2 * R_ * V_; i += 256) {
        const int j = i % (R_ * V_);
        const int r = j / V_, v = j % V_;
        const bool first = (i < R_ * V_);
        const float* w = first ? w1 : w2;
        float acc = first ? b1[r] : b2[r];
        #pragma unroll
        for (int c = 0; c < C_; ++c) acc += w[r * C_ + c] * xms[c][v];
        if (first) x1s[r][v] = acc;
        else       x2s[r][v] = acc;
    }
    __syncthreads();

    unsigned short* dn = dT + (size_t)n * O_ * DP * DP;
    for (int p = tid; p < DP * DP; p += 256) {       // p = v*32+u
        const int v = p >> 5, u = p & 31;
        if (u < V_ && v < V_) {
            float adjr[R_];
            #pragma unroll
            for (int r = 0; r < R_; ++r) adjr[r] = tanhf(x1s[r][u] - x2s[r][v]);
            const float a = A[u * V_ + v];
            #pragma unroll
            for (int oo = 0; oo < 8; ++oo) {
                const int o = og + oo;
                float acc = b4[o];
                #pragma unroll
                for (int r = 0; r < R_; ++r) acc = fmaf(w4[o * R_ + r], adjr[r], acc);
                dn[(size_t)o * DP * DP + p] = f2bf(acc + a);   // ALPHA == 1
            }
        } else {
            #pragma unroll
            for (int oo = 0; oo < 8; ++oo)
                dn[(size_t)(og + oo) * DP * DP + p] = 0;
        }
    }
}

// -------- k_F v6 (r13..r16, validated ~23us): B-frags = single b128 loads from
//          pre-transposed xT (in this block's own d_out region); x3b-only LDS.
__global__ __launch_bounds__(512) void k_F(const float* __restrict__ w3,
                                           const float* __restrict__ b3,
                                           const unsigned short* __restrict__ dT,
                                           float* io) {
    __shared__ __align__(16) unsigned short x3b[16 * X3S];        // 20736 B

    const int n    = blockIdx.y;
    const int tc   = blockIdx.x;
    const int tid  = threadIdx.x;
    const int lane = tid & 63;
    const int wave = tid >> 6;      // 0..7
    const int l16  = lane & 15;
    const int lg   = lane >> 4;     // 0..3

    // zero x3b u-pad [24,32): [25,32) must be 0 for GEMM2's K=32
    if (tid < 256) {
        const int o_l = tid >> 4, t = tid & 15;
        *(s8v*)&x3b[o_l * X3S + t * UPAD + 24] = (s8v)0;
    }
    __syncthreads();

    // ---- hoist B-frags: 8 independent b128 loads from xT
    const char* xTb = (const char*)io + (size_t)n * O_ * TV * 4 + (size_t)tc * 1600;
    s8v bfr[4][2];
    #pragma unroll
    for (int i = 0; i < 4; ++i) {
        const int nt = wave + 8 * i;
        if (nt < NT) {
            const int pos = nt * 16 + l16;
            #pragma unroll
            for (int kh = 0; kh < 2; ++kh) {
                const int L = pos * 128 + kh * 64 + lg * 16;
                const int row = L / 1600, off = L - row * 1600;
                bfr[i][kh] = *(const s8v*)(xTb + (size_t)row * (TV * 4) + off);
            }
        }
    }

    const unsigned short* dn = dT + (size_t)n * O_ * DP * DP;
    float* on = io + (size_t)n * O_ * TV + tc * NPOS;

    #pragma unroll 1
    for (int h = 0; h < 4; ++h) {               // o-quarter: o = h*16 .. h*16+15
        // A-frags (w3 L1/L2-resident)
        s8v afr[2];
        #pragma unroll
        for (int kh = 0; kh < 2; ++kh) {
            const float* wp = w3 + (h * 16 + l16) * C_ + kh * 32 + lg * 8;
            s8v f;
            #pragma unroll
            for (int j = 0; j < 8; ++j) f[j] = (short)f2bf(wp[j]);
            afr[kh] = f;
        }
        const f4v b3h = *(const f4v*)(b3 + h * 16 + lg * 4);

        // GEMM1 quarter
        #pragma unroll
        for (int i = 0; i < 4; ++i) {
            const int nt = wave + 8 * i;
            if (nt < NT) {
                const int pos = nt * 16 + l16;
                const int t = pos / 25, u = pos - 25 * t;
                f4v acc = (f4v)0.f;
                acc = __builtin_amdgcn_mfma_f32_16x16x32_bf16(afr[0], bfr[i][0], acc, 0, 0, 0);
                acc = __builtin_amdgcn_mfma_f32_16x16x32_bf16(afr[1], bfr[i][1], acc, 0, 0, 0);
                #pragma unroll
                for (int r = 0; r < 4; ++r)
                    x3b[(lg * 4 + r) * X3S + t * UPAD + u] = f2bf(acc[r] + b3h[r]);
            }
        }
        __syncthreads();   // B1: x3b ready (h=0: also fences xT reads vs stores)

        // GEMM2 quarter: wave owns o_l = wave*2 + {0,1}
        #pragma unroll
        for (int oo = 0; oo < 2; ++oo) {
            const int o_l = wave * 2 + oo;
            const int o_g = h * 16 + o_l;
            const unsigned short* dp = dn + (size_t)o_g * DP * DP;
            const s8v bv0 = *(const s8v*)(dp + l16 * DP + lg * 8);
            const s8v bv1 = *(const s8v*)(dp + (16 + l16) * DP + lg * 8);
            const s8v av  = *(const s8v*)&x3b[o_l * X3S + l16 * UPAD + lg * 8];
            f4v c0 = (f4v)0.f, c1 = (f4v)0.f;
            c0 = __builtin_amdgcn_mfma_f32_16x16x32_bf16(av, bv0, c0, 0, 0, 0);
            c1 = __builtin_amdgcn_mfma_f32_16x16x32_bf16(av, bv1, c1, 0, 0, 0);
            float* ob = on + (size_t)o_g * TV;
            #pragma unroll
            for (int r = 0; r < 4; ++r) {
                const int t = lg * 4 + r;                       // C: row=t, col=v
                ob[t * 25 + l16] = c0[r];
                if (l16 < 9) ob[t * 25 + 16 + l16] = c1[r];
            }
        }
        __syncthreads();   // B2: protect x3b before next quarter's GEMM1
    }
}

extern "C" void kernel_launch(void* const* d_in, const int* in_sizes, int n_in,
                              void* d_out, int out_size, void* d_ws, size_t ws_size,
                              hipStream_t stream) {
    const float* x  = (const float*)d_in[0];
    const float* A  = (const float*)d_in[1];
    const float* w1 = (const float*)d_in[2];
    const float* b1 = (const float*)d_in[3];
    const float* w2 = (const float*)d_in[4];
    const float* b2 = (const float*)d_in[5];
    const float* w3 = (const float*)d_in[6];
    const float* b3 = (const float*)d_in[7];
    const float* w4 = (const float*)d_in[8];
    const float* b4 = (const float*)d_in[9];

    float* out = (float*)d_out;
    float* xm  = (float*)d_ws;                                          // 0.41 MB f32
    unsigned short* dTm = (unsigned short*)(xm + (size_t)N_ * CV);      // 8.4 MB bf16
    float* xmp = (float*)(dTm + (size_t)N_ * O_ * DP * DP);             // 13.1 MB f32

    k_prep<<<dim3(32, N_), 256, 0, stream>>>(x, xmp, out);
    k_red<<<N_ * 4, 256, 0, stream>>>(xmp, xm);
    k_dmat<<<dim3(N_, 8), 256, 0, stream>>>(xm, A, w1, b1, w2, b2, w4, b4, dTm);
    k_F<<<dim3(T_ / TC, N_), 512, 0, stream>>>(w3, b3, dTm, out);
}

// Round 18
// 89.428 us; speedup vs baseline: 1.2368x; 1.0894x over previous
//
#include <hip/hip_runtime.h>

#define N_ 64
#define C_ 64
#define T_ 256
#define V_ 25
#define R_ 8
#define O_ 64
constexpr int TV = T_ * V_;           // 6400
constexpr float INV_T = 1.0f / (float)T_;
constexpr int TC = 16;                // t's per k_FF block
constexpr int NPOS = TC * V_;         // 400
constexpr int NT = NPOS / 16;         // 25 MFMA N-tiles
constexpr int DP = 32;                // padded u,v extent of dT
constexpr int UPAD = 40;              // u slots per (o,t) row in x3b
constexpr int X3S = 16 * UPAD + 8;    // 648 halfwords per o_local
constexpr int CV = C_ * V_;           // 1600
constexpr int XROW = 72;              // xs row stride in halfwords = 144B:
                                      // 16B-aligned b128 reads; bank step 4

typedef __attribute__((ext_vector_type(8))) short s8v;     // 8 bf16
typedef __attribute__((ext_vector_type(4))) float f4v;     // MFMA acc / float4

__device__ __forceinline__ unsigned short f2bf(float f) {   // RNE f32->bf16
    union { float f; unsigned u; } v; v.f = f;
    unsigned r = v.u + 0x7FFFu + ((v.u >> 16) & 1u);
    return (unsigned short)(r >> 16);
}

// -------- k_mean: xm[n][c][v] = mean_t x[n][c][t][v]  (r2-proven, ~19us)
__global__ __launch_bounds__(256) void k_mean(const float* __restrict__ x,
                                              float* __restrict__ xm) {
    __shared__ float part[8 * V_];
    const int bid = blockIdx.x;           // n*C + c
    const int tid = threadIdx.x;
    const float* xp = x + (size_t)bid * TV;
    if (tid < 200) {
        const int vid = tid % V_;
        const int seg = tid / V_;
        float s = 0.f;
        const float* p = xp + seg * 32 * V_ + vid;
        #pragma unroll
        for (int j = 0; j < 32; ++j) s += p[j * V_];
        part[tid] = s;
    }
    __syncthreads();
    if (tid < V_) {
        float s = 0.f;
        #pragma unroll
        for (int k = 0; k < 8; ++k) s += part[k * V_ + tid];
        xm[(size_t)bid * V_ + tid] = s * INV_T;
    }
}

// -------- k_dmat: dT[n][o][v][u] = d(u,v) bf16, zero-padded to 32x32. (r13+)
__global__ __launch_bounds__(256) void k_dmat(const float* __restrict__ xm,
                                              const float* __restrict__ A,
                                              const float* __restrict__ w1,
                                              const float* __restrict__ b1,
                                              const float* __restrict__ w2,
                                              const float* __restrict__ b2,
                                              const float* __restrict__ w4,
                                              const float* __restrict__ b4,
                                              unsigned short* __restrict__ dT) {
    __shared__ float xms[C_][V_];
    __shared__ float x1s[R_][V_];
    __shared__ float x2s[R_][V_];
    const int n  = blockIdx.x;
    const int og = blockIdx.y * 8;
    const int tid = threadIdx.x;

    for (int i = tid; i < C_ * V_; i += 256)
        xms[i / V_][i % V_] = xm[(size_t)n * C_ * V_ + i];
    __syncthreads();

    for (int i = tid; i < 2 * R_ * V_; i += 256) {
        const int j = i % (R_ * V_);
        const int r = j / V_, v = j % V_;
        const bool first = (i < R_ * V_);
        const float* w = first ? w1 : w2;
        float acc = first ? b1[r] : b2[r];
        #pragma unroll
        for (int c = 0; c < C_; ++c) acc += w[r * C_ + c] * xms[c][v];
        if (first) x1s[r][v] = acc;
        else       x2s[r][v] = acc;
    }
    __syncthreads();

    unsigned short* dn = dT + (size_t)n * O_ * DP * DP;
    for (int p = tid; p < DP * DP; p += 256) {       // p = v*32+u
        const int v = p >> 5, u = p & 31;
        if (u < V_ && v < V_) {
            float adjr[R_];
            #pragma unroll
            for (int r = 0; r < R_; ++r) adjr[r] = tanhf(x1s[r][u] - x2s[r][v]);
            const float a = A[u * V_ + v];
            #pragma unroll
            for (int oo = 0; oo < 8; ++oo) {
                const int o = og + oo;
                float acc = b4[o];
                #pragma unroll
                for (int r = 0; r < R_; ++r) acc = fmaf(w4[o * R_ + r], adjr[r], acc);
                dn[(size_t)o * DP * DP + p] = f2bf(acc + a);   // ALPHA == 1
            }
        } else {
            #pragma unroll
            for (int oo = 0; oo < 8; ++oo)
                dn[(size_t)(og + oo) * DP * DP + p] = 0;
        }
    }
}

// -------- k_FF: fused stage + GEMM1 + GEMM2. LDS xs[pos][c] (144B rows) so a
//          GEMM1 B-frag is ONE aligned ds_read_b128 (natural c-order — MFMA
//          math identical to the validated r13-17 k_F v6). Stage uses k_mean's
//          proven coalesced scalar-load pattern + 1 ds_write_u16 each.
//          78.3KB LDS, 512 thr -> 2 blocks/CU.
__global__ __launch_bounds__(512) void k_FF(const float* __restrict__ x,
                                            const float* __restrict__ w3,
                                            const float* __restrict__ b3,
                                            const unsigned short* __restrict__ dT,
                                            float* __restrict__ out) {
    __shared__ __align__(16) unsigned short xs[NPOS * XROW];      // 57600 B
    __shared__ __align__(16) unsigned short x3b[16 * X3S];        // 20736 B

    const int n    = blockIdx.y;
    const int tc   = blockIdx.x;
    const int tid  = threadIdx.x;
    const int lane = tid & 63;
    const int wave = tid >> 6;      // 0..7
    const int l16  = lane & 15;
    const int lg   = lane >> 4;     // 0..3

    // zero x3b u-pad [24,32): [25,32) must be 0 for GEMM2's K=32
    if (tid < 256) {
        const int o_l = tid >> 4, t = tid & 15;
        *(s8v*)&x3b[o_l * X3S + t * UPAD + 24] = (s8v)0;
    }

    // ---- stage x -> xs[pos][c]: 25600 items, coalesced scalar f32 loads
    //      (256B runs/wave, k_mean pattern), one ds_write_u16 each (bank
    //      step 4 -> ~8-way, ~300cyc/wave total).
    {
        const float* xb = x + (size_t)n * C_ * TV + tc * NPOS;
        #pragma unroll 4
        for (int i = 0; i < 50; ++i) {
            const int s = i * 512 + tid;          // exact: 50*512 == 25600
            const int c = s / NPOS, pm = s - c * NPOS;
            xs[pm * XROW + c] = f2bf(xb[(size_t)c * TV + pm]);
        }
    }
    __syncthreads();

    // ---- hoist B-frags: 8 single ds_read_b128 per wave
    s8v bfr[4][2];
    #pragma unroll
    for (int i = 0; i < 4; ++i) {
        const int nt = wave + 8 * i;
        if (nt < NT) {
            const int pos = nt * 16 + l16;
            #pragma unroll
            for (int kh = 0; kh < 2; ++kh)
                bfr[i][kh] = *(const s8v*)&xs[pos * XROW + kh * 32 + lg * 8];
        }
    }

    const unsigned short* dn = dT + (size_t)n * O_ * DP * DP;
    float* on = out + (size_t)n * O_ * TV + tc * NPOS;

    #pragma unroll 1
    for (int h = 0; h < 4; ++h) {               // o-quarter: o = h*16 .. h*16+15
        // A-frags (w3 L1/L2-resident; natural c-map, matches bfr)
        s8v afr[2];
        #pragma unroll
        for (int kh = 0; kh < 2; ++kh) {
            const float* wp = w3 + (h * 16 + l16) * C_ + kh * 32 + lg * 8;
            s8v f;
            #pragma unroll
            for (int j = 0; j < 8; ++j) f[j] = (short)f2bf(wp[j]);
            afr[kh] = f;
        }
        const f4v b3h = *(const f4v*)(b3 + h * 16 + lg * 4);

        // GEMM1 quarter
        #pragma unroll
        for (int i = 0; i < 4; ++i) {
            const int nt = wave + 8 * i;
            if (nt < NT) {
                const int pos = nt * 16 + l16;
                const int t = pos / 25, u = pos - 25 * t;
                f4v acc = (f4v)0.f;
                acc = __builtin_amdgcn_mfma_f32_16x16x32_bf16(afr[0], bfr[i][0], acc, 0, 0, 0);
                acc = __builtin_amdgcn_mfma_f32_16x16x32_bf16(afr[1], bfr[i][1], acc, 0, 0, 0);
                // C: col=l16=pos, row=lg*4+r=o-in-tile (verified layout)
                #pragma unroll
                for (int r = 0; r < 4; ++r)
                    x3b[(lg * 4 + r) * X3S + t * UPAD + u] = f2bf(acc[r] + b3h[r]);
            }
        }
        __syncthreads();   // B1: x3b(quarter h) ready

        // GEMM2 quarter: wave owns o_l = wave*2 + {0,1}; dT b128 from L2
        #pragma unroll
        for (int oo = 0; oo < 2; ++oo) {
            const int o_l = wave * 2 + oo;
            const int o_g = h * 16 + o_l;
            const unsigned short* dp = dn + (size_t)o_g * DP * DP;
            const s8v bv0 = *(const s8v*)(dp + l16 * DP + lg * 8);
            const s8v bv1 = *(const s8v*)(dp + (16 + l16) * DP + lg * 8);
            const s8v av  = *(const s8v*)&x3b[o_l * X3S + l16 * UPAD + lg * 8];
            f4v c0 = (f4v)0.f, c1 = (f4v)0.f;
            c0 = __builtin_amdgcn_mfma_f32_16x16x32_bf16(av, bv0, c0, 0, 0, 0);
            c1 = __builtin_amdgcn_mfma_f32_16x16x32_bf16(av, bv1, c1, 0, 0, 0);
            float* ob = on + (size_t)o_g * TV;
            #pragma unroll
            for (int r = 0; r < 4; ++r) {
                const int t = lg * 4 + r;                       // C: row=t, col=v
                ob[t * 25 + l16] = c0[r];
                if (l16 < 9) ob[t * 25 + 16 + l16] = c1[r];
            }
        }
        __syncthreads();   // B2: protect x3b before next quarter's GEMM1
    }
}

extern "C" void kernel_launch(void* const* d_in, const int* in_sizes, int n_in,
                              void* d_out, int out_size, void* d_ws, size_t ws_size,
                              hipStream_t stream) {
    const float* x  = (const float*)d_in[0];
    const float* A  = (const float*)d_in[1];
    const float* w1 = (const float*)d_in[2];
    const float* b1 = (const float*)d_in[3];
    const float* w2 = (const float*)d_in[4];
    const float* b2 = (const float*)d_in[5];
    const float* w3 = (const float*)d_in[6];
    const float* b3 = (const float*)d_in[7];
    const float* w4 = (const float*)d_in[8];
    const float* b4 = (const float*)d_in[9];

    float* out = (float*)d_out;
    float* xm  = (float*)d_ws;                                          // 0.41 MB f32
    unsigned short* dTm = (unsigned short*)(xm + (size_t)N_ * CV);      // 8.4 MB bf16

    k_mean<<<N_ * C_, 256, 0, stream>>>(x, xm);
    k_dmat<<<dim3(N_, 8), 256, 0, stream>>>(xm, A, w1, b1, w2, b2, w4, b4, dTm);
    k_FF<<<dim3(T_ / TC, N_), 512, 0, stream>>>(x, w3, b3, dTm, out);
}